// Round 15
// baseline (76.681 us; speedup 1.0000x reference)
//
#include <hip/hip_runtime.h>
#include <hip/hip_bf16.h>
#include <math.h>

#define NPTS   262144
#define UNITS  256
#define STR    15          // rect row stride in prep power-build (deg<=14)
#define NCO    225         // 15*15 rect slots per unit-net build
#define LSTR   16          // padded output row stride (float4-exact)
#define OFF_PU 0           // pred u: rows 0..12 -> 13*16 = 208
#define OFF_LU 208         // lap  u: rows 0..14 -> 15*16 = 240
#define OFF_PV 448
#define OFF_LV 656
#define CFTOT  896         // total padded coefficient floats
#define PBLK   64          // prep blocks (4 waves each, 1 unit/wave, 2 nets)
#define MTPB   256
#define MBLK   512         // main blocks; MBLK*MTPB*2 == NPTS (PPT=2)
#define PPTOFF 131072      // second-point offset

// deg-6 Taylor of e^-t about t=1.1 (monomial coeffs); |err| <= 4e-4 on t in [-0.2,2.4]
__device__ __constant__ float CC[8] = {
    0.99985117f, -0.99903214f, 0.49728235f, -0.16237637f,
    0.03751734f, -0.00582524f, 0.00046232f, 0.0f };

// tiny counter-zero kernel (replaces hipMemsetAsync, whose fill kernel costs ~39us)
__global__ void rbf_init(unsigned* __restrict__ cnt)
{
    if (threadIdx.x < 2) cnt[threadIdx.x] = 0u;
}

// ---------------------------------------------------------------------------
// prep: wave w of block bid owns unit j = bid*4+w; builds BOTH nets
// sequentially, accumulating monomial-coefficient sums in registers.
// LAST block folds the 64 partials into coefF (fixed order, deterministic).
// ---------------------------------------------------------------------------
__global__ __launch_bounds__(256) void rbf_prep(
    const float* __restrict__ mu_u, const float* __restrict__ beta_u,
    const float* __restrict__ W_u,
    const float* __restrict__ mu_v, const float* __restrict__ beta_v,
    const float* __restrict__ W_v,
    float* __restrict__ partial, int* __restrict__ flagBlk,
    float* __restrict__ coefF, int* __restrict__ flagAll,
    unsigned* __restrict__ cnt)
{
    const int tid  = threadIdx.x;
    const int bid  = blockIdx.x;
    const int w    = tid >> 6;
    const int lane = tid & 63;
    const int j    = bid * 4 + w;          // unit 0..255

    __shared__ float pwA[4][NCO];
    __shared__ float pwB[4][NCO];
    __shared__ int   sflag[4];
    __shared__ int   amLast;

    int cidx[4], gi[4], gm[4];
    #pragma unroll
    for (int r = 0; r < 4; ++r) {
        const int c = lane + 64 * r;
        cidx[r] = c;
        gi[r]   = c / STR;
        gm[r]   = c - STR * gi[r];
    }

    float accPu[4] = {0,0,0,0}, accLu[4] = {0,0,0,0};
    float accPv[4] = {0,0,0,0}, accLv[4] = {0,0,0,0};
    int badAll = 0;

    #pragma unroll
    for (int s = 0; s < 2; ++s) {
        const float* mu = s ? mu_v   : mu_u;
        const float* be = s ? beta_v : beta_u;
        const float* W  = s ? W_v    : W_u;
        const float mx  = mu[j], my = mu[UNITS + j];
        const float b   = be[j], wgt = W[j];

        // validity of deg-6 approx over safety box [-0.05,1.05]^2
        const float xlo = -0.05f, xhi = 1.05f;
        const float dxl = xlo - mx, dxh = xhi - mx;
        const float dyl = xlo - my, dyh = xhi - my;
        const float dx2max = fmaxf(dxl*dxl, dxh*dxh);
        const float dy2max = fmaxf(dyl*dyl, dyh*dyh);
        const float dx2min = (dxl <= 0.f && dxh >= 0.f) ? 0.f : fminf(dxl*dxl, dxh*dxh);
        const float dy2min = (dyl <= 0.f && dyh >= 0.f) ? 0.f : fminf(dyl*dyl, dyh*dyh);
        const float t1 = b * (dx2min + dy2min);
        const float t2 = b * (dx2max + dy2max);
        const float tlo = fminf(t1, t2), thi = fmaxf(t1, t2);
        badAll |= !(thi <= 2.4f && tlo >= -0.2f);

        const float ax = mx - 0.5f, ay = my - 0.5f;
        const float qXX = b, qYY = b;
        const float qX = -2.f*b*ax, qY = -2.f*b*ay;
        const float q0 = b*(ax*ax + ay*ay);

        const float fourwb = 4.f * wgt * b;
        float cP[8], cL[8];
        #pragma unroll
        for (int m = 0; m < 8; ++m) {
            cP[m] = wgt * CC[m];
            cL[m] = fourwb * ((m ? CC[m-1] : 0.f) - CC[m]);
        }

        float* A = &pwA[w][0];
        float* B = &pwB[w][0];
        #pragma unroll
        for (int r = 0; r < 4; ++r) {
            const int c = cidx[r];
            if (c < NCO) {
                float v = 0.f;
                if (c == 0)          v = q0;
                else if (c == 1)     v = qY;
                else if (c == 2)     v = qYY;
                else if (c == STR)   v = qX;
                else if (c == 2*STR) v = qXX;
                A[c] = v;
            }
        }
        __threadfence_block();

        float aP[4] = {0,0,0,0}, aL[4] = {0,0,0,0};
        #pragma unroll
        for (int r = 0; r < 4; ++r)
            if (cidx[r] == 0) { aP[r] = cP[0]; aL[r] = cL[0]; }

        #pragma unroll
        for (int m = 1; m <= 7; ++m) {
            #pragma unroll
            for (int r = 0; r < 4; ++r) {
                const int c = cidx[r];
                if (c < NCO) {
                    const float p = A[c];
                    aP[r] = fmaf(cP[m], p, aP[r]);
                    aL[r] = fmaf(cL[m], p, aL[r]);
                }
            }
            if (m < 7) {
                #pragma unroll
                for (int r = 0; r < 4; ++r) {
                    const int c = cidx[r];
                    if (c < NCO) {
                        float acc = q0 * A[c];
                        if (gm[r] >= 1) acc = fmaf(qY,  A[c-1],     acc);
                        if (gm[r] >= 2) acc = fmaf(qYY, A[c-2],     acc);
                        if (gi[r] >= 1) acc = fmaf(qX,  A[c-STR],   acc);
                        if (gi[r] >= 2) acc = fmaf(qXX, A[c-2*STR], acc);
                        B[c] = acc;
                    }
                }
                float* T = A; A = B; B = T;
                __threadfence_block();
            }
        }
        #pragma unroll
        for (int r = 0; r < 4; ++r) {
            if (s == 0) { accPu[r] = aP[r]; accLu[r] = aL[r]; }
            else        { accPv[r] = aP[r]; accLv[r] = aL[r]; }
        }
        __threadfence_block();
    }
    if (lane == 0) sflag[w] = badAll;

    // ---- stage net-u accs, write PU+LU regions ----
    __syncthreads();
    #pragma unroll
    for (int r = 0; r < 4; ++r) {
        const int c = cidx[r];
        if (c < NCO) { pwA[w][c] = accPu[r]; pwB[w][c] = accLu[r]; }
    }
    __syncthreads();
    if (tid < 448) {
        float v = 0.f;
        if (tid < 208) {                 // PU: rows 0..12
            const int i = tid >> 4, m = tid & 15;
            if (m < 15) {
                const int c = i*STR + m;
                v = pwA[0][c] + pwA[1][c] + pwA[2][c] + pwA[3][c];
            }
        } else {                         // LU: rows 0..14
            const int idx = tid - 208;
            const int i = idx >> 4, m = idx & 15;
            if (m < 15) {
                const int c = i*STR + m;
                v = pwB[0][c] + pwB[1][c] + pwB[2][c] + pwB[3][c];
            }
        }
        partial[bid * CFTOT + tid] = v;
    }
    // ---- stage net-v accs, write PV+LV regions ----
    __syncthreads();
    #pragma unroll
    for (int r = 0; r < 4; ++r) {
        const int c = cidx[r];
        if (c < NCO) { pwA[w][c] = accPv[r]; pwB[w][c] = accLv[r]; }
    }
    __syncthreads();
    if (tid < 448) {
        float v = 0.f;
        if (tid < 208) {
            const int i = tid >> 4, m = tid & 15;
            if (m < 15) {
                const int c = i*STR + m;
                v = pwA[0][c] + pwA[1][c] + pwA[2][c] + pwA[3][c];
            }
        } else {
            const int idx = tid - 208;
            const int i = idx >> 4, m = idx & 15;
            if (m < 15) {
                const int c = i*STR + m;
                v = pwB[0][c] + pwB[1][c] + pwB[2][c] + pwB[3][c];
            }
        }
        partial[bid * CFTOT + 448 + tid] = v;
    }
    if (tid == 0)
        flagBlk[bid] = sflag[0] | sflag[1] | sflag[2] | sflag[3];

    // ---- last-block fold (deterministic fixed-order sum; R10-proven) ----
    __syncthreads();
    __threadfence();
    if (tid == 0) {
        const unsigned old = atomicAdd(cnt, 1u);
        amLast = (old == PBLK - 1);
    }
    __syncthreads();
    if (amLast) {
        __threadfence();
        for (int c = tid; c < CFTOT; c += 256) {
            float s = 0.f;
            #pragma unroll 8
            for (int p = 0; p < PBLK; ++p)
                s += partial[p * CFTOT + c];
            coefF[c] = s;
        }
        if (tid == 0) {
            int f = 0;
            for (int p = 0; p < PBLK; ++p) f |= flagBlk[p];
            *flagAll = f;
        }
        __threadfence();
    }
}

// ---------------------------------------------------------------------------
// eval2: padded stride-16 bivariate poly (total degree D) at 2 points from
// LDS float4 broadcast reads (one ds_read_b128 feeds 8 FMAs).
// ---------------------------------------------------------------------------
template<int D>
__device__ __forceinline__ void eval2(const float* sco,
    float X0, float X1, float Y0, float Y1, float& h0, float& h1)
{
    h0 = h1 = 0.f;
    #pragma unroll
    for (int ii = 0; ii <= D; ++ii) {
        const int i = D - ii;
        const int K = (D - i + 4) / 4;
        float r0 = 0.f, r1 = 0.f;
        #pragma unroll
        for (int kk = 0; kk < K; ++kk) {
            const int k = K - 1 - kk;
            const float4 q = *(const float4*)(sco + i*LSTR + 4*k);
            r0 = fmaf(r0, Y0, q.w); r1 = fmaf(r1, Y1, q.w);
            r0 = fmaf(r0, Y0, q.z); r1 = fmaf(r1, Y1, q.z);
            r0 = fmaf(r0, Y0, q.y); r1 = fmaf(r1, Y1, q.y);
            r0 = fmaf(r0, Y0, q.x); r1 = fmaf(r1, Y1, q.x);
        }
        h0 = fmaf(h0, X0, r0); h1 = fmaf(h1, X1, r1);
    }
}

__global__ __launch_bounds__(MTPB) void rbf_main(
    const float* __restrict__ gx, const float* __restrict__ gy,
    const float* __restrict__ gu, const float* __restrict__ gv,
    const float* __restrict__ gdu, const float* __restrict__ gdv,
    const float* __restrict__ coefF, const int* __restrict__ flagAll,
    const float* __restrict__ mu_u, const float* __restrict__ beta_u,
    const float* __restrict__ W_u,
    const float* __restrict__ mu_v, const float* __restrict__ beta_v,
    const float* __restrict__ W_v,
    const float* __restrict__ p_d, const float* __restrict__ p_a,
    const float* __restrict__ p_b, const float* __restrict__ p_um,
    const float* __restrict__ p_vm, const float* __restrict__ p_us,
    const float* __restrict__ p_vs,
    float* __restrict__ part, float* __restrict__ out,
    unsigned* __restrict__ cnt)
{
    const int tid = threadIdx.x;
    const int bid = blockIdx.x;
    const int i0  = bid * MTPB + tid;
    const int i1  = i0 + PPTOFF;

    __shared__ __align__(16) float sco[CFTOT];  // 3.6 KB coef table
    __shared__ float red[4][6];
    __shared__ int amLast;
    if (tid < CFTOT/4)
        ((float4*)sco)[tid] = ((const float4*)coefF)[tid];
    __syncthreads();

    const float x0 = gx[i0], y0 = gy[i0];
    const float x1 = gx[i1], y1 = gy[i1];
    const int bad = __builtin_amdgcn_readfirstlane(*flagAll);
    const bool inBox =
        (x0 >= -0.05f) && (x0 <= 1.05f) && (y0 >= -0.05f) && (y0 <= 1.05f) &&
        (x1 >= -0.05f) && (x1 <= 1.05f) && (y1 >= -0.05f) && (y1 <= 1.05f);
    const bool allIn = __all(inBox);

    float up0, vp0, lu0, lv0, up1, vp1, lu1, lv1;
    if (!bad && allIn) {
        const float X0 = x0 - 0.5f, Y0 = y0 - 0.5f;
        const float X1 = x1 - 0.5f, Y1 = y1 - 0.5f;
        eval2<12>(sco + OFF_PU, X0, X1, Y0, Y1, up0, up1);
        eval2<14>(sco + OFF_LU, X0, X1, Y0, Y1, lu0, lu1);
        eval2<12>(sco + OFF_PV, X0, X1, Y0, Y1, vp0, vp1);
        eval2<14>(sco + OFF_LV, X0, X1, Y0, Y1, lv0, lv1);
    } else {
        // exact whole-wave fallback (never taken for in-distribution inputs)
        up0=lu0=vp0=lv0=up1=lu1=vp1=lv1=0.f;
        for (int jj = 0; jj < UNITS; ++jj) {
            const float mxu = mu_u[jj], myu = mu_u[UNITS + jj];
            const float bu_ = beta_u[jj], wu_ = W_u[jj];
            const float mxv = mu_v[jj], myv = mu_v[UNITS + jj];
            const float bv_ = beta_v[jj], wv_ = W_v[jj];
            {
                float dx = x0 - mxu, dy = y0 - myu;
                float r2 = fmaf(dx, dx, dy * dy);
                float ph = expf(-bu_ * r2);
                up0 = fmaf(wu_, ph, up0);
                lu0 = fmaf(wu_ * ph, fmaf(4.f*bu_*bu_, r2, -4.f*bu_), lu0);
                dx = x1 - mxu; dy = y1 - myu;
                r2 = fmaf(dx, dx, dy * dy);
                ph = expf(-bu_ * r2);
                up1 = fmaf(wu_, ph, up1);
                lu1 = fmaf(wu_ * ph, fmaf(4.f*bu_*bu_, r2, -4.f*bu_), lu1);
            }
            {
                float dx = x0 - mxv, dy = y0 - myv;
                float r2 = fmaf(dx, dx, dy * dy);
                float ph = expf(-bv_ * r2);
                vp0 = fmaf(wv_, ph, vp0);
                lv0 = fmaf(wv_ * ph, fmaf(4.f*bv_*bv_, r2, -4.f*bv_), lv0);
                dx = x1 - mxv; dy = y1 - myv;
                r2 = fmaf(dx, dx, dy * dy);
                ph = expf(-bv_ * r2);
                vp1 = fmaf(wv_, ph, vp1);
                lv1 = fmaf(wv_ * ph, fmaf(4.f*bv_*bv_, r2, -4.f*bv_), lv1);
            }
        }
    }

    // ---- residuals ----
    const float dd = p_d[0],  aa = p_a[0], bb = p_b[0];
    const float um = p_um[0], vm = p_vm[0];
    const float us = p_us[0], vs = p_vs[0];
    const float iu  = 1.0f / us, iv = 1.0f / vs;
    const float cau = (aa - um) * iu;
    const float c4b = 4.0f * bb * iu;
    const float cbv = bb * iv;

    float s0 = 0.f, s1 = 0.f, s2 = 0.f, s3 = 0.f, s4 = 0.f, s5 = 0.f;
    {
        const float uu = gu[i0], vv = gv[i0];
        const float ddu = gdu[i0], ddv = gdv[i0];
        float eu = up0 - uu; s0 += eu * eu;
        float ev = vp0 - vv; s1 += ev * ev;
        float uph = fmaf(up0, us, um);
        float vph = fmaf(vp0, vs, vm);
        float den = fmaf(uph, uph, 1.0f);
        float uvd = uph * vph / den;
        float rpu = fmaf(dd, lu0, cau) - up0 - c4b * uvd;
        s2 += rpu * rpu;
        float rdu = lu0 - ddu; s3 += rdu * rdu;
        float rpv = fmaf(uph, iv, lv0) - cbv * uvd;
        s4 += rpv * rpv;
        float rdv = lv0 - ddv; s5 += rdv * rdv;
    }
    {
        const float uu = gu[i1], vv = gv[i1];
        const float ddu = gdu[i1], ddv = gdv[i1];
        float eu = up1 - uu; s0 += eu * eu;
        float ev = vp1 - vv; s1 += ev * ev;
        float uph = fmaf(up1, us, um);
        float vph = fmaf(vp1, vs, vm);
        float den = fmaf(uph, uph, 1.0f);
        float uvd = uph * vph / den;
        float rpu = fmaf(dd, lu1, cau) - up1 - c4b * uvd;
        s2 += rpu * rpu;
        float rdu = lu1 - ddu; s3 += rdu * rdu;
        float rpv = fmaf(uph, iv, lv1) - cbv * uvd;
        s4 += rpv * rpv;
        float rdv = lv1 - ddv; s5 += rdv * rdv;
    }

    // ---- block reduction (deterministic) ----
    float s[6] = { s0, s1, s2, s3, s4, s5 };
    #pragma unroll
    for (int k = 0; k < 6; ++k) {
        float vsum = s[k];
        for (int off = 32; off > 0; off >>= 1)
            vsum += __shfl_down(vsum, off);
        s[k] = vsum;
    }
    const int lane = tid & 63;
    const int wid  = tid >> 6;
    if (lane == 0) {
        #pragma unroll
        for (int k = 0; k < 6; ++k) red[wid][k] = s[k];
    }
    __syncthreads();
    if (tid < 6) {
        float p = red[0][tid] + red[1][tid] + red[2][tid] + red[3][tid];
        part[tid * MBLK + bid] = p;
    }

    // ---- last-block final reduction (deterministic; R10-proven pattern) ----
    __syncthreads();
    __threadfence();
    if (tid == 0) {
        const unsigned old = atomicAdd(cnt, 1u);
        amLast = (old == MBLK - 1);
    }
    __syncthreads();
    if (amLast) {
        __threadfence();
        float t[6];
        #pragma unroll
        for (int k = 0; k < 6; ++k) {
            const float* p = part + k * MBLK;
            float vsum = p[tid] + p[tid + 256];
            for (int off = 32; off > 0; off >>= 1)
                vsum += __shfl_down(vsum, off);
            t[k] = vsum;
        }
        if (lane == 0) {
            #pragma unroll
            for (int k = 0; k < 6; ++k) red[wid][k] = t[k];
        }
        __syncthreads();
        if (tid == 0) {
            const float inv = 1.0f / (float)NPTS;
            const float Lu  = (red[0][0] + red[1][0] + red[2][0] + red[3][0]) * inv;
            const float Lv  = (red[0][1] + red[1][1] + red[2][1] + red[3][1]) * inv;
            const float Lpu = (red[0][2] + red[1][2] + red[2][2] + red[3][2]) * inv;
            const float Ldu = (red[0][3] + red[1][3] + red[2][3] + red[3][3]) * inv;
            const float Lpv = (red[0][4] + red[1][4] + red[2][4] + red[3][4]) * inv;
            const float Ldv = (red[0][5] + red[1][5] + red[2][5] + red[3][5]) * inv;
            out[0] = 0.1f * Lu + 0.1f * Lv + Lpu + Ldu + Lpv + Ldv;
            out[1] = Lu;
            out[2] = Lpu;
            out[3] = Lv;
            out[4] = Lpv;
            out[5] = Ldu;
            out[6] = Ldv;
        }
    }
}

extern "C" void kernel_launch(void* const* d_in, const int* in_sizes, int n_in,
                              void* d_out, int out_size, void* d_ws, size_t ws_size,
                              hipStream_t stream) {
    const float* gx   = (const float*)d_in[0];
    const float* gy   = (const float*)d_in[1];
    const float* gu   = (const float*)d_in[2];
    const float* gv   = (const float*)d_in[3];
    const float* gdu  = (const float*)d_in[4];
    const float* gdv  = (const float*)d_in[5];
    const float* mu_u = (const float*)d_in[6];
    const float* be_u = (const float*)d_in[7];
    const float* W_u  = (const float*)d_in[8];
    const float* mu_v = (const float*)d_in[9];
    const float* be_v = (const float*)d_in[10];
    const float* W_v  = (const float*)d_in[11];
    const float* p_d  = (const float*)d_in[12];
    const float* p_a  = (const float*)d_in[13];
    const float* p_b  = (const float*)d_in[14];
    const float* p_um = (const float*)d_in[15];
    const float* p_vm = (const float*)d_in[16];
    const float* p_us = (const float*)d_in[17];
    const float* p_vs = (const float*)d_in[18];

    float* wsf     = (float*)d_ws;
    float* partial = wsf;                        // 64*896 = 57344 floats
    float* coefF   = wsf + 57344;                // 896 floats (16B aligned)
    float* part    = wsf + 58240;                // 6*512 floats
    int*   flagBlk = (int*)(wsf + 61312);        // 64 ints
    int*   flagAll = (int*)(wsf + 61376);        // 1 int
    unsigned* cnt  = (unsigned*)(wsf + 61377);   // 2 counters
    float* out     = (float*)d_out;              // 7 floats

    rbf_init<<<1, 64, 0, stream>>>(cnt);
    rbf_prep<<<PBLK, 256, 0, stream>>>(mu_u, be_u, W_u, mu_v, be_v, W_v,
                                       partial, flagBlk, coefF, flagAll, cnt);
    rbf_main<<<MBLK, MTPB, 0, stream>>>(gx, gy, gu, gv, gdu, gdv,
                                        coefF, flagAll,
                                        mu_u, be_u, W_u, mu_v, be_v, W_v,
                                        p_d, p_a, p_b, p_um, p_vm, p_us, p_vs,
                                        part, out, cnt + 1);
}

// Round 16
// 37.753 us; speedup vs baseline: 2.0311x; 2.0311x over previous
//
#include <hip/hip_runtime.h>
#include <hip/hip_bf16.h>
#include <math.h>

#define NPTS   262144
#define UNITS  256
#define STR    15          // rect row stride in prep power-build (deg<=14)
#define NCO    225         // 15*15 rect slots per unit-net build
#define OFF_PU 0           // padded: pred u rows 0..12 -> 13*16 = 208
#define OFF_LU 208         // lap  u rows 0..14 -> 15*16 = 240
#define OFF_PV 448
#define OFF_LV 656
#define CFTOT  896         // padded coefficient floats (partial layout)
#define NQ_TOT 128         // compact quads: 28 + 36 + 28 + 36
#define PBLK   64          // prep blocks (4 waves each, 1 unit/wave, 2 nets)
#define MTPB   256
#define MBLK   256         // main blocks; each handles 1024 points
#define TILE   1024

// deg-6 Taylor of e^-t about t=1.1 (monomial coeffs); |err| <= 4e-4 on t in [-0.2,2.4]
__device__ __constant__ float CC[8] = {
    0.99985117f, -0.99903214f, 0.49728235f, -0.16237637f,
    0.03751734f, -0.00582524f, 0.00046232f, 0.0f };

// ---------------------------------------------------------------------------
// prep: wave w of block bid owns unit j = bid*4+w; builds BOTH nets
// sequentially, accumulating monomial-coefficient sums in registers.
// (verbatim R12 structure — proven)
// ---------------------------------------------------------------------------
__global__ __launch_bounds__(256) void rbf_prep(
    const float* __restrict__ mu_u, const float* __restrict__ beta_u,
    const float* __restrict__ W_u,
    const float* __restrict__ mu_v, const float* __restrict__ beta_v,
    const float* __restrict__ W_v,
    float* __restrict__ partial, int* __restrict__ flagBlk)
{
    const int tid  = threadIdx.x;
    const int bid  = blockIdx.x;
    const int w    = tid >> 6;
    const int lane = tid & 63;
    const int j    = bid * 4 + w;          // unit 0..255

    __shared__ float pwA[4][NCO];
    __shared__ float pwB[4][NCO];
    __shared__ int   sflag[4];

    int cidx[4], gi[4], gm[4];
    #pragma unroll
    for (int r = 0; r < 4; ++r) {
        const int c = lane + 64 * r;
        cidx[r] = c;
        gi[r]   = c / STR;
        gm[r]   = c - STR * gi[r];
    }

    float accPu[4] = {0,0,0,0}, accLu[4] = {0,0,0,0};
    float accPv[4] = {0,0,0,0}, accLv[4] = {0,0,0,0};
    int badAll = 0;

    #pragma unroll
    for (int s = 0; s < 2; ++s) {
        const float* mu = s ? mu_v   : mu_u;
        const float* be = s ? beta_v : beta_u;
        const float* W  = s ? W_v    : W_u;
        const float mx  = mu[j], my = mu[UNITS + j];
        const float b   = be[j], wgt = W[j];

        // validity of deg-6 approx over safety box [-0.05,1.05]^2
        const float xlo = -0.05f, xhi = 1.05f;
        const float dxl = xlo - mx, dxh = xhi - mx;
        const float dyl = xlo - my, dyh = xhi - my;
        const float dx2max = fmaxf(dxl*dxl, dxh*dxh);
        const float dy2max = fmaxf(dyl*dyl, dyh*dyh);
        const float dx2min = (dxl <= 0.f && dxh >= 0.f) ? 0.f : fminf(dxl*dxl, dxh*dxh);
        const float dy2min = (dyl <= 0.f && dyh >= 0.f) ? 0.f : fminf(dyl*dyl, dyh*dyh);
        const float t1 = b * (dx2min + dy2min);
        const float t2 = b * (dx2max + dy2max);
        const float tlo = fminf(t1, t2), thi = fmaxf(t1, t2);
        badAll |= !(thi <= 2.4f && tlo >= -0.2f);

        const float ax = mx - 0.5f, ay = my - 0.5f;
        const float qXX = b, qYY = b;
        const float qX = -2.f*b*ax, qY = -2.f*b*ay;
        const float q0 = b*(ax*ax + ay*ay);

        const float fourwb = 4.f * wgt * b;
        float cP[8], cL[8];
        #pragma unroll
        for (int m = 0; m < 8; ++m) {
            cP[m] = wgt * CC[m];
            cL[m] = fourwb * ((m ? CC[m-1] : 0.f) - CC[m]);
        }

        float* A = &pwA[w][0];
        float* B = &pwB[w][0];
        #pragma unroll
        for (int r = 0; r < 4; ++r) {
            const int c = cidx[r];
            if (c < NCO) {
                float v = 0.f;
                if (c == 0)          v = q0;
                else if (c == 1)     v = qY;
                else if (c == 2)     v = qYY;
                else if (c == STR)   v = qX;
                else if (c == 2*STR) v = qXX;
                A[c] = v;
            }
        }
        __threadfence_block();

        float aP[4] = {0,0,0,0}, aL[4] = {0,0,0,0};
        #pragma unroll
        for (int r = 0; r < 4; ++r)
            if (cidx[r] == 0) { aP[r] = cP[0]; aL[r] = cL[0]; }

        #pragma unroll
        for (int m = 1; m <= 7; ++m) {
            #pragma unroll
            for (int r = 0; r < 4; ++r) {
                const int c = cidx[r];
                if (c < NCO) {
                    const float p = A[c];
                    aP[r] = fmaf(cP[m], p, aP[r]);
                    aL[r] = fmaf(cL[m], p, aL[r]);
                }
            }
            if (m < 7) {
                #pragma unroll
                for (int r = 0; r < 4; ++r) {
                    const int c = cidx[r];
                    if (c < NCO) {
                        float acc = q0 * A[c];
                        if (gm[r] >= 1) acc = fmaf(qY,  A[c-1],     acc);
                        if (gm[r] >= 2) acc = fmaf(qYY, A[c-2],     acc);
                        if (gi[r] >= 1) acc = fmaf(qX,  A[c-STR],   acc);
                        if (gi[r] >= 2) acc = fmaf(qXX, A[c-2*STR], acc);
                        B[c] = acc;
                    }
                }
                float* T = A; A = B; B = T;
                __threadfence_block();
            }
        }
        #pragma unroll
        for (int r = 0; r < 4; ++r) {
            if (s == 0) { accPu[r] = aP[r]; accLu[r] = aL[r]; }
            else        { accPv[r] = aP[r]; accLv[r] = aL[r]; }
        }
        __threadfence_block();
    }
    if (lane == 0) sflag[w] = badAll;

    // ---- stage net-u accs, write PU+LU regions (padded layout) ----
    __syncthreads();
    #pragma unroll
    for (int r = 0; r < 4; ++r) {
        const int c = cidx[r];
        if (c < NCO) { pwA[w][c] = accPu[r]; pwB[w][c] = accLu[r]; }
    }
    __syncthreads();
    if (tid < 448) {
        float v = 0.f;
        if (tid < 208) {                 // PU: rows 0..12
            const int i = tid >> 4, m = tid & 15;
            if (m < 15) {
                const int c = i*STR + m;
                v = pwA[0][c] + pwA[1][c] + pwA[2][c] + pwA[3][c];
            }
        } else {                         // LU: rows 0..14
            const int idx = tid - 208;
            const int i = idx >> 4, m = idx & 15;
            if (m < 15) {
                const int c = i*STR + m;
                v = pwB[0][c] + pwB[1][c] + pwB[2][c] + pwB[3][c];
            }
        }
        partial[bid * CFTOT + tid] = v;
    }
    // ---- stage net-v accs, write PV+LV regions ----
    __syncthreads();
    #pragma unroll
    for (int r = 0; r < 4; ++r) {
        const int c = cidx[r];
        if (c < NCO) { pwA[w][c] = accPv[r]; pwB[w][c] = accLv[r]; }
    }
    __syncthreads();
    if (tid < 448) {
        float v = 0.f;
        if (tid < 208) {
            const int i = tid >> 4, m = tid & 15;
            if (m < 15) {
                const int c = i*STR + m;
                v = pwA[0][c] + pwA[1][c] + pwA[2][c] + pwA[3][c];
            }
        } else {
            const int idx = tid - 208;
            const int i = idx >> 4, m = idx & 15;
            if (m < 15) {
                const int c = i*STR + m;
                v = pwB[0][c] + pwB[1][c] + pwB[2][c] + pwB[3][c];
            }
        }
        partial[bid * CFTOT + 448 + tid] = v;
    }
    if (tid == 0)
        flagBlk[bid] = sflag[0] | sflag[1] | sflag[2] | sflag[3];
}

// ---------------------------------------------------------------------------
// fold: 64 partials -> COMPACT per-poly quad table (128 float4 = 512 floats).
// compact quads: PU[0..27], LU[28..63], PV[64..91], LV[92..127]; within a
// poly, rows i=0..D concatenated, K(i)=(D-i+4)/4 quads per row.
// ---------------------------------------------------------------------------
__global__ __launch_bounds__(256) void rbf_fold(
    const float* __restrict__ partial, const int* __restrict__ flagBlk,
    float* __restrict__ compact, int* __restrict__ flagAll)
{
    const int tid = threadIdx.x;
    const int c   = blockIdx.x * 256 + tid;       // 0..511 compact float idx
    if (c < NQ_TOT * 4) {
        const int quad = c >> 2, e = c & 3;
        int D, qloc, padOFF;
        if (quad < 28)      { D = 12; qloc = quad;      padOFF = OFF_PU; }
        else if (quad < 64) { D = 14; qloc = quad - 28; padOFF = OFF_LU; }
        else if (quad < 92) { D = 12; qloc = quad - 64; padOFF = OFF_PV; }
        else                { D = 14; qloc = quad - 92; padOFF = OFF_LV; }
        int i = 0;
        while (qloc >= (D - i + 4) / 4) { qloc -= (D - i + 4) / 4; ++i; }
        const int pidx = padOFF + i * 16 + 4 * qloc + e;
        float s = 0.f;
        #pragma unroll 8
        for (int p = 0; p < PBLK; ++p)
            s += partial[p * CFTOT + pidx];
        compact[c] = s;
    }
    if (blockIdx.x == 0 && tid < 64) {
        int f = flagBlk[tid];
        for (int off = 32; off > 0; off >>= 1)
            f |= __shfl_down(f, off);
        if (tid == 0) *flagAll = f;
    }
}

// ---------------------------------------------------------------------------
// wave_poly_eval: one WAVE evaluates one poly (register-resident compact
// quads, fully static indexing) at all TILE points (2 points in flight).
// ---------------------------------------------------------------------------
template<int D>
__device__ __forceinline__ void wave_poly_eval(
    const float4* __restrict__ Cg, const float* sX, const float* sY,
    float* resRow, int lane)
{
    constexpr int NQ = (D == 12) ? 28 : 36;
    float4 q[NQ];
    #pragma unroll
    for (int k = 0; k < NQ; ++k) q[k] = Cg[k];

    for (int b = 0; b < TILE; b += 128) {
        const int p0 = b + lane, p1 = b + 64 + lane;
        const float X0 = sX[p0], Y0 = sY[p0];
        const float X1 = sX[p1], Y1 = sY[p1];
        float h0 = 0.f, h1 = 0.f;
        int off = NQ;
        #pragma unroll
        for (int ii = 0; ii <= D; ++ii) {
            const int i = D - ii;                 // row, high X-degree first
            const int K = (ii + 4) / 4;           // quads in row i
            off -= K;
            float r0 = 0.f, r1 = 0.f;
            #pragma unroll
            for (int kk = K - 1; kk >= 0; --kk) {
                const float4 cq = q[off + kk];
                r0 = fmaf(r0, Y0, cq.w); r1 = fmaf(r1, Y1, cq.w);
                r0 = fmaf(r0, Y0, cq.z); r1 = fmaf(r1, Y1, cq.z);
                r0 = fmaf(r0, Y0, cq.y); r1 = fmaf(r1, Y1, cq.y);
                r0 = fmaf(r0, Y0, cq.x); r1 = fmaf(r1, Y1, cq.x);
            }
            h0 = fmaf(h0, X0, r0); h1 = fmaf(h1, X1, r1);
        }
        resRow[p0] = h0; resRow[p1] = h1;
    }
}

__global__ __launch_bounds__(MTPB, 1) void rbf_main(
    const float* __restrict__ gx, const float* __restrict__ gy,
    const float* __restrict__ gu, const float* __restrict__ gv,
    const float* __restrict__ gdu, const float* __restrict__ gdv,
    const float* __restrict__ compact, const int* __restrict__ flagAll,
    const float* __restrict__ mu_u, const float* __restrict__ beta_u,
    const float* __restrict__ W_u,
    const float* __restrict__ mu_v, const float* __restrict__ beta_v,
    const float* __restrict__ W_v,
    const float* __restrict__ p_d, const float* __restrict__ p_a,
    const float* __restrict__ p_b, const float* __restrict__ p_um,
    const float* __restrict__ p_vm, const float* __restrict__ p_us,
    const float* __restrict__ p_vs,
    float* __restrict__ part)
{
    const int tid  = threadIdx.x;
    const int bid  = blockIdx.x;
    const int base = bid * TILE;
    const int lane = tid & 63;
    const int wid  = __builtin_amdgcn_readfirstlane(tid >> 6);

    __shared__ float sX[TILE];
    __shared__ float sY[TILE];
    __shared__ float res[4 * TILE];   // up, lu, vp, lv rows
    __shared__ float red[4][6];

    // stage centered coords + box check
    int myOut = (*flagAll != 0);
    #pragma unroll
    for (int k = 0; k < 4; ++k) {
        const int p = tid + 256 * k;
        const float x = gx[base + p], y = gy[base + p];
        sX[p] = x - 0.5f; sY[p] = y - 0.5f;
        myOut |= !((x >= -0.05f) && (x <= 1.05f) &&
                   (y >= -0.05f) && (y <= 1.05f));
    }
    const int blockBad = __syncthreads_or(myOut);

    if (!blockBad) {
        const float4* cq = (const float4*)compact;
        switch (wid) {
            case 0: wave_poly_eval<12>(cq,      sX, sY, res,            lane); break;
            case 1: wave_poly_eval<14>(cq + 28, sX, sY, res + TILE,     lane); break;
            case 2: wave_poly_eval<12>(cq + 64, sX, sY, res + 2*TILE,   lane); break;
            default: wave_poly_eval<14>(cq + 92, sX, sY, res + 3*TILE,  lane); break;
        }
    } else {
        // exact whole-block fallback (never taken for in-distribution inputs)
        #pragma unroll
        for (int k = 0; k < 4; ++k) {
            const int p = tid + 256 * k;
            const float x = sX[p] + 0.5f, y = sY[p] + 0.5f;
            float up = 0.f, lu = 0.f, vp = 0.f, lv = 0.f;
            for (int jj = 0; jj < UNITS; ++jj) {
                {
                    const float dx = x - mu_u[jj], dy = y - mu_u[UNITS + jj];
                    const float bb_ = beta_u[jj], ww = W_u[jj];
                    const float r2 = fmaf(dx, dx, dy * dy);
                    const float ph = expf(-bb_ * r2);
                    up = fmaf(ww, ph, up);
                    lu = fmaf(ww * ph, fmaf(4.f*bb_*bb_, r2, -4.f*bb_), lu);
                }
                {
                    const float dx = x - mu_v[jj], dy = y - mu_v[UNITS + jj];
                    const float bb_ = beta_v[jj], ww = W_v[jj];
                    const float r2 = fmaf(dx, dx, dy * dy);
                    const float ph = expf(-bb_ * r2);
                    vp = fmaf(ww, ph, vp);
                    lv = fmaf(ww * ph, fmaf(4.f*bb_*bb_, r2, -4.f*bb_), lv);
                }
            }
            res[p] = up; res[TILE + p] = lu;
            res[2*TILE + p] = vp; res[3*TILE + p] = lv;
        }
    }
    __syncthreads();

    // ---- residuals over this thread's 4 points ----
    const float dd = p_d[0],  aa = p_a[0], bb = p_b[0];
    const float um = p_um[0], vm = p_vm[0];
    const float us = p_us[0], vs = p_vs[0];
    const float iu  = 1.0f / us, iv = 1.0f / vs;
    const float cau = (aa - um) * iu;
    const float c4b = 4.0f * bb * iu;
    const float cbv = bb * iv;

    float s0 = 0.f, s1 = 0.f, s2 = 0.f, s3 = 0.f, s4 = 0.f, s5 = 0.f;
    #pragma unroll
    for (int k = 0; k < 4; ++k) {
        const int p  = tid + 256 * k;
        const int gi_ = base + p;
        const float up = res[p],          lu = res[TILE + p];
        const float vp = res[2*TILE + p], lv = res[3*TILE + p];
        const float uu  = gu[gi_],  vv  = gv[gi_];
        const float ddu = gdu[gi_], ddv = gdv[gi_];
        float eu = up - uu; s0 += eu * eu;
        float ev = vp - vv; s1 += ev * ev;
        float uph = fmaf(up, us, um);
        float vph = fmaf(vp, vs, vm);
        float den = fmaf(uph, uph, 1.0f);
        float uvd = uph * vph / den;
        float rpu = fmaf(dd, lu, cau) - up - c4b * uvd;
        s2 += rpu * rpu;
        float rdu = lu - ddu; s3 += rdu * rdu;
        float rpv = fmaf(uph, iv, lv) - cbv * uvd;
        s4 += rpv * rpv;
        float rdv = lv - ddv; s5 += rdv * rdv;
    }

    // ---- block reduction (deterministic) ----
    float s[6] = { s0, s1, s2, s3, s4, s5 };
    #pragma unroll
    for (int k = 0; k < 6; ++k) {
        float vsum = s[k];
        for (int off = 32; off > 0; off >>= 1)
            vsum += __shfl_down(vsum, off);
        s[k] = vsum;
    }
    const int wrow = tid >> 6;
    if (lane == 0) {
        #pragma unroll
        for (int k = 0; k < 6; ++k) red[wrow][k] = s[k];
    }
    __syncthreads();
    if (tid < 6) {
        float p = red[0][tid] + red[1][tid] + red[2][tid] + red[3][tid];
        part[tid * MBLK + bid] = p;
    }
}

__global__ __launch_bounds__(256) void rbf_final(
    const float* __restrict__ part, float* __restrict__ out)
{
    const int tid = threadIdx.x;
    __shared__ float red[4][6];
    float s[6];
    #pragma unroll
    for (int k = 0; k < 6; ++k) {
        float vsum = part[k * MBLK + tid];
        for (int off = 32; off > 0; off >>= 1)
            vsum += __shfl_down(vsum, off);
        s[k] = vsum;
    }
    const int lane = tid & 63;
    const int wid  = tid >> 6;
    if (lane == 0) {
        #pragma unroll
        for (int k = 0; k < 6; ++k) red[wid][k] = s[k];
    }
    __syncthreads();
    if (tid == 0) {
        const float inv = 1.0f / (float)NPTS;
        const float Lu  = (red[0][0] + red[1][0] + red[2][0] + red[3][0]) * inv;
        const float Lv  = (red[0][1] + red[1][1] + red[2][1] + red[3][1]) * inv;
        const float Lpu = (red[0][2] + red[1][2] + red[2][2] + red[3][2]) * inv;
        const float Ldu = (red[0][3] + red[1][3] + red[2][3] + red[3][3]) * inv;
        const float Lpv = (red[0][4] + red[1][4] + red[2][4] + red[3][4]) * inv;
        const float Ldv = (red[0][5] + red[1][5] + red[2][5] + red[3][5]) * inv;
        out[0] = 0.1f * Lu + 0.1f * Lv + Lpu + Ldu + Lpv + Ldv;
        out[1] = Lu;
        out[2] = Lpu;
        out[3] = Lv;
        out[4] = Lpv;
        out[5] = Ldu;
        out[6] = Ldv;
    }
}

extern "C" void kernel_launch(void* const* d_in, const int* in_sizes, int n_in,
                              void* d_out, int out_size, void* d_ws, size_t ws_size,
                              hipStream_t stream) {
    const float* gx   = (const float*)d_in[0];
    const float* gy   = (const float*)d_in[1];
    const float* gu   = (const float*)d_in[2];
    const float* gv   = (const float*)d_in[3];
    const float* gdu  = (const float*)d_in[4];
    const float* gdv  = (const float*)d_in[5];
    const float* mu_u = (const float*)d_in[6];
    const float* be_u = (const float*)d_in[7];
    const float* W_u  = (const float*)d_in[8];
    const float* mu_v = (const float*)d_in[9];
    const float* be_v = (const float*)d_in[10];
    const float* W_v  = (const float*)d_in[11];
    const float* p_d  = (const float*)d_in[12];
    const float* p_a  = (const float*)d_in[13];
    const float* p_b  = (const float*)d_in[14];
    const float* p_um = (const float*)d_in[15];
    const float* p_vm = (const float*)d_in[16];
    const float* p_us = (const float*)d_in[17];
    const float* p_vs = (const float*)d_in[18];

    float* wsf     = (float*)d_ws;
    float* partial = wsf;                        // 64*896 = 57344 floats
    float* compact = wsf + 57344;                // 512 floats (16B aligned)
    float* part    = wsf + 57856;                // 6*256 floats
    int*   flagBlk = (int*)(wsf + 59392);        // 64 ints
    int*   flagAll = (int*)(wsf + 59456);        // 1 int
    float* out     = (float*)d_out;              // 7 floats

    rbf_prep<<<PBLK, 256, 0, stream>>>(mu_u, be_u, W_u, mu_v, be_v, W_v,
                                       partial, flagBlk);
    rbf_fold<<<2, 256, 0, stream>>>(partial, flagBlk, compact, flagAll);
    rbf_main<<<MBLK, MTPB, 0, stream>>>(gx, gy, gu, gv, gdu, gdv,
                                        compact, flagAll,
                                        mu_u, be_u, W_u, mu_v, be_v, W_v,
                                        p_d, p_a, p_b, p_um, p_vm, p_us, p_vs,
                                        part);
    rbf_final<<<1, 256, 0, stream>>>(part, out);
}

// Round 17
// 27.656 us; speedup vs baseline: 2.7727x; 1.3651x over previous
//
#include <hip/hip_runtime.h>
#include <hip/hip_bf16.h>
#include <math.h>

#define NPTS   262144
#define UNITS  256
#define STR    15          // rect row stride in prep power-build (deg<=14)
#define NCO    225         // 15*15 rect slots per unit-net build
#define LSTR   16          // padded output row stride (float4-exact)
#define OFF_PU 0           // pred u: rows 0..12 -> 13*16 = 208
#define OFF_LU 208         // lap  u: rows 0..14 -> 15*16 = 240
#define OFF_PV 448
#define OFF_LV 656
#define CFTOT  896         // total padded coefficient floats
#define PBLK   64          // prep blocks (4 waves each, 1 unit/wave, 2 nets)
#define PPT    4           // points per thread in main
#define MTPB   256
#define MBLK   256         // main blocks; MBLK*MTPB*PPT == NPTS
#define QSTRIDE 65536      // point stride between a thread's 4 points

// deg-6 Taylor of e^-t about t=1.1 (monomial coeffs); |err| <= 4e-4 on t in [-0.2,2.4]
__device__ __constant__ float CC[8] = {
    0.99985117f, -0.99903214f, 0.49728235f, -0.16237637f,
    0.03751734f, -0.00582524f, 0.00046232f, 0.0f };

// ---------------------------------------------------------------------------
// prep: wave w of block bid owns unit j = bid*4+w; builds BOTH nets
// sequentially, accumulating monomial-coefficient sums in registers.
// (verbatim R12 — proven)
// ---------------------------------------------------------------------------
__global__ __launch_bounds__(256) void rbf_prep(
    const float* __restrict__ mu_u, const float* __restrict__ beta_u,
    const float* __restrict__ W_u,
    const float* __restrict__ mu_v, const float* __restrict__ beta_v,
    const float* __restrict__ W_v,
    float* __restrict__ partial, int* __restrict__ flagBlk)
{
    const int tid  = threadIdx.x;
    const int bid  = blockIdx.x;
    const int w    = tid >> 6;
    const int lane = tid & 63;
    const int j    = bid * 4 + w;          // unit 0..255

    __shared__ float pwA[4][NCO];
    __shared__ float pwB[4][NCO];
    __shared__ int   sflag[4];

    int cidx[4], gi[4], gm[4];
    #pragma unroll
    for (int r = 0; r < 4; ++r) {
        const int c = lane + 64 * r;
        cidx[r] = c;
        gi[r]   = c / STR;
        gm[r]   = c - STR * gi[r];
    }

    float accPu[4] = {0,0,0,0}, accLu[4] = {0,0,0,0};
    float accPv[4] = {0,0,0,0}, accLv[4] = {0,0,0,0};
    int badAll = 0;

    #pragma unroll
    for (int s = 0; s < 2; ++s) {
        const float* mu = s ? mu_v   : mu_u;
        const float* be = s ? beta_v : beta_u;
        const float* W  = s ? W_v    : W_u;
        const float mx  = mu[j], my = mu[UNITS + j];
        const float b   = be[j], wgt = W[j];

        // validity of deg-6 approx over safety box [-0.05,1.05]^2
        const float xlo = -0.05f, xhi = 1.05f;
        const float dxl = xlo - mx, dxh = xhi - mx;
        const float dyl = xlo - my, dyh = xhi - my;
        const float dx2max = fmaxf(dxl*dxl, dxh*dxh);
        const float dy2max = fmaxf(dyl*dyl, dyh*dyh);
        const float dx2min = (dxl <= 0.f && dxh >= 0.f) ? 0.f : fminf(dxl*dxl, dxh*dxh);
        const float dy2min = (dyl <= 0.f && dyh >= 0.f) ? 0.f : fminf(dyl*dyl, dyh*dyh);
        const float t1 = b * (dx2min + dy2min);
        const float t2 = b * (dx2max + dy2max);
        const float tlo = fminf(t1, t2), thi = fmaxf(t1, t2);
        badAll |= !(thi <= 2.4f && tlo >= -0.2f);

        const float ax = mx - 0.5f, ay = my - 0.5f;
        const float qXX = b, qYY = b;
        const float qX = -2.f*b*ax, qY = -2.f*b*ay;
        const float q0 = b*(ax*ax + ay*ay);

        const float fourwb = 4.f * wgt * b;
        float cP[8], cL[8];
        #pragma unroll
        for (int m = 0; m < 8; ++m) {
            cP[m] = wgt * CC[m];
            cL[m] = fourwb * ((m ? CC[m-1] : 0.f) - CC[m]);
        }

        float* A = &pwA[w][0];
        float* B = &pwB[w][0];
        #pragma unroll
        for (int r = 0; r < 4; ++r) {
            const int c = cidx[r];
            if (c < NCO) {
                float v = 0.f;
                if (c == 0)          v = q0;
                else if (c == 1)     v = qY;
                else if (c == 2)     v = qYY;
                else if (c == STR)   v = qX;
                else if (c == 2*STR) v = qXX;
                A[c] = v;
            }
        }
        __threadfence_block();

        float aP[4] = {0,0,0,0}, aL[4] = {0,0,0,0};
        #pragma unroll
        for (int r = 0; r < 4; ++r)
            if (cidx[r] == 0) { aP[r] = cP[0]; aL[r] = cL[0]; }

        #pragma unroll
        for (int m = 1; m <= 7; ++m) {
            #pragma unroll
            for (int r = 0; r < 4; ++r) {
                const int c = cidx[r];
                if (c < NCO) {
                    const float p = A[c];
                    aP[r] = fmaf(cP[m], p, aP[r]);
                    aL[r] = fmaf(cL[m], p, aL[r]);
                }
            }
            if (m < 7) {
                #pragma unroll
                for (int r = 0; r < 4; ++r) {
                    const int c = cidx[r];
                    if (c < NCO) {
                        float acc = q0 * A[c];
                        if (gm[r] >= 1) acc = fmaf(qY,  A[c-1],     acc);
                        if (gm[r] >= 2) acc = fmaf(qYY, A[c-2],     acc);
                        if (gi[r] >= 1) acc = fmaf(qX,  A[c-STR],   acc);
                        if (gi[r] >= 2) acc = fmaf(qXX, A[c-2*STR], acc);
                        B[c] = acc;
                    }
                }
                float* T = A; A = B; B = T;
                __threadfence_block();
            }
        }
        #pragma unroll
        for (int r = 0; r < 4; ++r) {
            if (s == 0) { accPu[r] = aP[r]; accLu[r] = aL[r]; }
            else        { accPv[r] = aP[r]; accLv[r] = aL[r]; }
        }
        __threadfence_block();
    }
    if (lane == 0) sflag[w] = badAll;

    // ---- stage net-u accs, write PU+LU regions ----
    __syncthreads();
    #pragma unroll
    for (int r = 0; r < 4; ++r) {
        const int c = cidx[r];
        if (c < NCO) { pwA[w][c] = accPu[r]; pwB[w][c] = accLu[r]; }
    }
    __syncthreads();
    if (tid < 448) {
        float v = 0.f;
        if (tid < 208) {                 // PU: rows 0..12
            const int i = tid >> 4, m = tid & 15;
            if (m < 15) {
                const int c = i*STR + m;
                v = pwA[0][c] + pwA[1][c] + pwA[2][c] + pwA[3][c];
            }
        } else {                         // LU: rows 0..14
            const int idx = tid - 208;
            const int i = idx >> 4, m = idx & 15;
            if (m < 15) {
                const int c = i*STR + m;
                v = pwB[0][c] + pwB[1][c] + pwB[2][c] + pwB[3][c];
            }
        }
        partial[bid * CFTOT + tid] = v;
    }
    // ---- stage net-v accs, write PV+LV regions ----
    __syncthreads();
    #pragma unroll
    for (int r = 0; r < 4; ++r) {
        const int c = cidx[r];
        if (c < NCO) { pwA[w][c] = accPv[r]; pwB[w][c] = accLv[r]; }
    }
    __syncthreads();
    if (tid < 448) {
        float v = 0.f;
        if (tid < 208) {
            const int i = tid >> 4, m = tid & 15;
            if (m < 15) {
                const int c = i*STR + m;
                v = pwA[0][c] + pwA[1][c] + pwA[2][c] + pwA[3][c];
            }
        } else {
            const int idx = tid - 208;
            const int i = idx >> 4, m = idx & 15;
            if (m < 15) {
                const int c = i*STR + m;
                v = pwB[0][c] + pwB[1][c] + pwB[2][c] + pwB[3][c];
            }
        }
        partial[bid * CFTOT + 448 + tid] = v;
    }
    if (tid == 0)
        flagBlk[bid] = sflag[0] | sflag[1] | sflag[2] | sflag[3];
}

// ---------------------------------------------------------------------------
// fold: 64 block-partials -> coefF (fixed order) + flagAll. 4 blocks.
// (verbatim R12 — proven)
// ---------------------------------------------------------------------------
__global__ __launch_bounds__(256) void rbf_fold(
    const float* __restrict__ partial, const int* __restrict__ flagBlk,
    float* __restrict__ coefF, int* __restrict__ flagAll)
{
    const int tid = threadIdx.x;
    const int c   = blockIdx.x * 256 + tid;
    if (c < CFTOT) {
        float s = 0.f;
        #pragma unroll 8
        for (int p = 0; p < PBLK; ++p)
            s += partial[p * CFTOT + c];
        coefF[c] = s;
    }
    if (blockIdx.x == 0 && tid < 64) {
        int f = flagBlk[tid];
        for (int off = 32; off > 0; off >>= 1)
            f |= __shfl_down(f, off);
        if (tid == 0) *flagAll = f;
    }
}

// ---------------------------------------------------------------------------
// eval4: padded (stride-16) bivariate poly, total degree D, at 4 points.
// One ds_read_b128 (uniform broadcast) feeds 16 FMAs; 4 independent
// Horner chains give the ILP that hides LDS latency at 1 wave/SIMD.
// (R9-proven structure, ported to the deg-6 table)
// ---------------------------------------------------------------------------
template<int D>
__device__ __forceinline__ void eval4(const float* sco,
    float X0, float X1, float X2, float X3,
    float Y0, float Y1, float Y2, float Y3,
    float& h0, float& h1, float& h2, float& h3)
{
    h0 = h1 = h2 = h3 = 0.f;
    #pragma unroll
    for (int ii = 0; ii <= D; ++ii) {
        const int i = D - ii;                 // row, high X-degree first
        const int K = (D - i + 4) / 4;        // quads needed in this row
        float r0 = 0.f, r1 = 0.f, r2 = 0.f, r3 = 0.f;
        #pragma unroll
        for (int kk = 0; kk < K; ++kk) {
            const int k = K - 1 - kk;
            const float4 q = *(const float4*)(sco + i*LSTR + 4*k);
            r0 = fmaf(r0, Y0, q.w); r1 = fmaf(r1, Y1, q.w);
            r2 = fmaf(r2, Y2, q.w); r3 = fmaf(r3, Y3, q.w);
            r0 = fmaf(r0, Y0, q.z); r1 = fmaf(r1, Y1, q.z);
            r2 = fmaf(r2, Y2, q.z); r3 = fmaf(r3, Y3, q.z);
            r0 = fmaf(r0, Y0, q.y); r1 = fmaf(r1, Y1, q.y);
            r2 = fmaf(r2, Y2, q.y); r3 = fmaf(r3, Y3, q.y);
            r0 = fmaf(r0, Y0, q.x); r1 = fmaf(r1, Y1, q.x);
            r2 = fmaf(r2, Y2, q.x); r3 = fmaf(r3, Y3, q.x);
        }
        h0 = fmaf(h0, X0, r0); h1 = fmaf(h1, X1, r1);
        h2 = fmaf(h2, X2, r2); h3 = fmaf(h3, X3, r3);
    }
}

__global__ __launch_bounds__(MTPB) void rbf_main(
    const float* __restrict__ gx, const float* __restrict__ gy,
    const float* __restrict__ gu, const float* __restrict__ gv,
    const float* __restrict__ gdu, const float* __restrict__ gdv,
    const float* __restrict__ coefF, const int* __restrict__ flagAll,
    const float* __restrict__ mu_u, const float* __restrict__ beta_u,
    const float* __restrict__ W_u,
    const float* __restrict__ mu_v, const float* __restrict__ beta_v,
    const float* __restrict__ W_v,
    const float* __restrict__ p_d, const float* __restrict__ p_a,
    const float* __restrict__ p_b, const float* __restrict__ p_um,
    const float* __restrict__ p_vm, const float* __restrict__ p_us,
    const float* __restrict__ p_vs,
    float* __restrict__ part)
{
    const int tid = threadIdx.x;
    const int bid = blockIdx.x;
    const int i0  = bid * MTPB + tid;

    __shared__ __align__(16) float sco[CFTOT];  // 3.6 KB coef table
    if (tid < CFTOT/4)
        ((float4*)sco)[tid] = ((const float4*)coefF)[tid];
    __syncthreads();

    float xs[PPT], ys[PPT];
    #pragma unroll
    for (int p = 0; p < PPT; ++p) {
        xs[p] = gx[i0 + p*QSTRIDE];
        ys[p] = gy[i0 + p*QSTRIDE];
    }

    const int bad = __builtin_amdgcn_readfirstlane(*flagAll);
    bool in = true;
    #pragma unroll
    for (int p = 0; p < PPT; ++p)
        in = in && (xs[p] >= -0.05f) && (xs[p] <= 1.05f)
                && (ys[p] >= -0.05f) && (ys[p] <= 1.05f);
    const bool allIn = __all(in);

    float up[PPT], vp[PPT], lu[PPT], lv[PPT];
    if (!bad && allIn) {
        const float X0 = xs[0]-0.5f, X1 = xs[1]-0.5f, X2 = xs[2]-0.5f, X3 = xs[3]-0.5f;
        const float Y0 = ys[0]-0.5f, Y1 = ys[1]-0.5f, Y2 = ys[2]-0.5f, Y3 = ys[3]-0.5f;
        eval4<12>(sco + OFF_PU, X0,X1,X2,X3, Y0,Y1,Y2,Y3, up[0],up[1],up[2],up[3]);
        eval4<14>(sco + OFF_LU, X0,X1,X2,X3, Y0,Y1,Y2,Y3, lu[0],lu[1],lu[2],lu[3]);
        eval4<12>(sco + OFF_PV, X0,X1,X2,X3, Y0,Y1,Y2,Y3, vp[0],vp[1],vp[2],vp[3]);
        eval4<14>(sco + OFF_LV, X0,X1,X2,X3, Y0,Y1,Y2,Y3, lv[0],lv[1],lv[2],lv[3]);
    } else {
        // exact whole-wave fallback (never taken for in-distribution inputs)
        #pragma unroll
        for (int p = 0; p < PPT; ++p) { up[p]=lu[p]=vp[p]=lv[p]=0.f; }
        for (int jj = 0; jj < UNITS; ++jj) {
            const float mxu = mu_u[jj], myu = mu_u[UNITS + jj];
            const float bu_ = beta_u[jj], wu_ = W_u[jj];
            const float mxv = mu_v[jj], myv = mu_v[UNITS + jj];
            const float bv_ = beta_v[jj], wv_ = W_v[jj];
            #pragma unroll
            for (int p = 0; p < PPT; ++p) {
                {
                    const float dx = xs[p] - mxu, dy = ys[p] - myu;
                    const float r2 = fmaf(dx, dx, dy * dy);
                    const float ph = expf(-bu_ * r2);
                    up[p] = fmaf(wu_, ph, up[p]);
                    lu[p] = fmaf(wu_ * ph, fmaf(4.f*bu_*bu_, r2, -4.f*bu_), lu[p]);
                }
                {
                    const float dx = xs[p] - mxv, dy = ys[p] - myv;
                    const float r2 = fmaf(dx, dx, dy * dy);
                    const float ph = expf(-bv_ * r2);
                    vp[p] = fmaf(wv_, ph, vp[p]);
                    lv[p] = fmaf(wv_ * ph, fmaf(4.f*bv_*bv_, r2, -4.f*bv_), lv[p]);
                }
            }
        }
    }

    // ---- residuals ----
    const float dd = p_d[0],  aa = p_a[0], bb = p_b[0];
    const float um = p_um[0], vm = p_vm[0];
    const float us = p_us[0], vs = p_vs[0];
    const float iu  = 1.0f / us, iv = 1.0f / vs;
    const float cau = (aa - um) * iu;
    const float c4b = 4.0f * bb * iu;
    const float cbv = bb * iv;

    float s0 = 0.f, s1 = 0.f, s2 = 0.f, s3 = 0.f, s4 = 0.f, s5 = 0.f;
    #pragma unroll
    for (int p = 0; p < PPT; ++p) {
        const int ii = i0 + p*QSTRIDE;
        const float uu  = gu[ii],  vv  = gv[ii];
        const float ddu = gdu[ii], ddv = gdv[ii];
        float eu = up[p] - uu; s0 += eu * eu;
        float ev = vp[p] - vv; s1 += ev * ev;
        float uph = fmaf(up[p], us, um);
        float vph = fmaf(vp[p], vs, vm);
        float den = fmaf(uph, uph, 1.0f);
        float uvd = uph * vph / den;
        float rpu = fmaf(dd, lu[p], cau) - up[p] - c4b * uvd;
        s2 += rpu * rpu;
        float rdu = lu[p] - ddu; s3 += rdu * rdu;
        float rpv = fmaf(uph, iv, lv[p]) - cbv * uvd;
        s4 += rpv * rpv;
        float rdv = lv[p] - ddv; s5 += rdv * rdv;
    }

    // ---- block reduction (deterministic) ----
    float s[6] = { s0, s1, s2, s3, s4, s5 };
    __shared__ float red[4][6];
    #pragma unroll
    for (int k = 0; k < 6; ++k) {
        float vsum = s[k];
        for (int off = 32; off > 0; off >>= 1)
            vsum += __shfl_down(vsum, off);
        s[k] = vsum;
    }
    const int lane = tid & 63;
    const int wid  = tid >> 6;
    if (lane == 0) {
        #pragma unroll
        for (int k = 0; k < 6; ++k) red[wid][k] = s[k];
    }
    __syncthreads();
    if (tid < 6) {
        float p = red[0][tid] + red[1][tid] + red[2][tid] + red[3][tid];
        part[tid * MBLK + bid] = p;
    }
}

__global__ __launch_bounds__(256) void rbf_final(
    const float* __restrict__ part, float* __restrict__ out)
{
    const int tid = threadIdx.x;
    __shared__ float red[4][6];
    float s[6];
    #pragma unroll
    for (int k = 0; k < 6; ++k) {
        float vsum = part[k * MBLK + tid];
        for (int off = 32; off > 0; off >>= 1)
            vsum += __shfl_down(vsum, off);
        s[k] = vsum;
    }
    const int lane = tid & 63;
    const int wid  = tid >> 6;
    if (lane == 0) {
        #pragma unroll
        for (int k = 0; k < 6; ++k) red[wid][k] = s[k];
    }
    __syncthreads();
    if (tid == 0) {
        const float inv = 1.0f / (float)NPTS;
        const float Lu  = (red[0][0] + red[1][0] + red[2][0] + red[3][0]) * inv;
        const float Lv  = (red[0][1] + red[1][1] + red[2][1] + red[3][1]) * inv;
        const float Lpu = (red[0][2] + red[1][2] + red[2][2] + red[3][2]) * inv;
        const float Ldu = (red[0][3] + red[1][3] + red[2][3] + red[3][3]) * inv;
        const float Lpv = (red[0][4] + red[1][4] + red[2][4] + red[3][4]) * inv;
        const float Ldv = (red[0][5] + red[1][5] + red[2][5] + red[3][5]) * inv;
        out[0] = 0.1f * Lu + 0.1f * Lv + Lpu + Ldu + Lpv + Ldv;
        out[1] = Lu;
        out[2] = Lpu;
        out[3] = Lv;
        out[4] = Lpv;
        out[5] = Ldu;
        out[6] = Ldv;
    }
}

extern "C" void kernel_launch(void* const* d_in, const int* in_sizes, int n_in,
                              void* d_out, int out_size, void* d_ws, size_t ws_size,
                              hipStream_t stream) {
    const float* gx   = (const float*)d_in[0];
    const float* gy   = (const float*)d_in[1];
    const float* gu   = (const float*)d_in[2];
    const float* gv   = (const float*)d_in[3];
    const float* gdu  = (const float*)d_in[4];
    const float* gdv  = (const float*)d_in[5];
    const float* mu_u = (const float*)d_in[6];
    const float* be_u = (const float*)d_in[7];
    const float* W_u  = (const float*)d_in[8];
    const float* mu_v = (const float*)d_in[9];
    const float* be_v = (const float*)d_in[10];
    const float* W_v  = (const float*)d_in[11];
    const float* p_d  = (const float*)d_in[12];
    const float* p_a  = (const float*)d_in[13];
    const float* p_b  = (const float*)d_in[14];
    const float* p_um = (const float*)d_in[15];
    const float* p_vm = (const float*)d_in[16];
    const float* p_us = (const float*)d_in[17];
    const float* p_vs = (const float*)d_in[18];

    float* wsf     = (float*)d_ws;
    float* partial = wsf;                        // 64*896 = 57344 floats
    float* coefF   = wsf + 57344;                // 896 floats (16B aligned)
    float* part    = wsf + 58240;                // 6*256 floats
    int*   flagBlk = (int*)(wsf + 59776);        // 64 ints
    int*   flagAll = (int*)(wsf + 59840);        // 1 int
    float* out     = (float*)d_out;              // 7 floats

    rbf_prep<<<PBLK, 256, 0, stream>>>(mu_u, be_u, W_u, mu_v, be_v, W_v,
                                       partial, flagBlk);
    rbf_fold<<<4, 256, 0, stream>>>(partial, flagBlk, coefF, flagAll);
    rbf_main<<<MBLK, MTPB, 0, stream>>>(gx, gy, gu, gv, gdu, gdv,
                                        coefF, flagAll,
                                        mu_u, be_u, W_u, mu_v, be_v, W_v,
                                        p_d, p_a, p_b, p_um, p_vm, p_us, p_vs,
                                        part);
    rbf_final<<<1, 256, 0, stream>>>(part, out);
}

// Round 18
// 26.894 us; speedup vs baseline: 2.8512x; 1.0283x over previous
//
#include <hip/hip_runtime.h>
#include <hip/hip_bf16.h>
#include <math.h>

#define NPTS   262144
#define UNITS  256
#define STR    15          // rect row stride in prep power-build (deg<=14)
#define NCO    225         // 15*15 rect slots per unit-net build
#define LSTR   16          // padded output row stride (float4-exact)
#define OFF_PU 0           // pred u: rows 0..12 -> 13*16 = 208
#define OFF_LU 208         // lap  u: rows 0..14 -> 15*16 = 240
#define OFF_PV 448
#define OFF_LV 656
#define CFTOT  896         // total padded coefficient floats
#define PBLK   128         // prep blocks (4 waves each, ONE (j,net) per wave)
#define PPT    4           // points per thread in main
#define MTPB   256
#define MBLK   256         // main blocks; MBLK*MTPB*PPT == NPTS
#define QSTRIDE 65536      // point stride between a thread's 4 points

// deg-6 Taylor of e^-t about t=1.1 (monomial coeffs); |err| <= 4e-4 on t in [-0.2,2.4]
__device__ __constant__ float CC[8] = {
    0.99985117f, -0.99903214f, 0.49728235f, -0.16237637f,
    0.03751734f, -0.00582524f, 0.00046232f, 0.0f };

// ---------------------------------------------------------------------------
// prep: wave w of block bid owns task id = bid*4+w -> unit j = id>>1,
// net = id&1 (u-waves: w=0,2 ; v-waves: w=1,3). ONE 7-iteration power-conv
// per wave (half the serial depth of the 2-net version), one staging pass.
// ---------------------------------------------------------------------------
__global__ __launch_bounds__(256) void rbf_prep(
    const float* __restrict__ mu_u, const float* __restrict__ beta_u,
    const float* __restrict__ W_u,
    const float* __restrict__ mu_v, const float* __restrict__ beta_v,
    const float* __restrict__ W_v,
    float* __restrict__ partial, int* __restrict__ flagBlk)
{
    const int tid  = threadIdx.x;
    const int bid  = blockIdx.x;
    const int w    = tid >> 6;
    const int lane = tid & 63;
    const int id   = bid * 4 + w;          // 0..511
    const int j    = id >> 1;              // unit
    const int net  = id & 1;               // 0 = u, 1 = v

    __shared__ float pwA[4][NCO];
    __shared__ float pwB[4][NCO];
    __shared__ int   sflag[4];

    int cidx[4], gi[4], gm[4];
    #pragma unroll
    for (int r = 0; r < 4; ++r) {
        const int c = lane + 64 * r;
        cidx[r] = c;
        gi[r]   = c / STR;
        gm[r]   = c - STR * gi[r];
    }

    const float* mu = net ? mu_v   : mu_u;
    const float* be = net ? beta_v : beta_u;
    const float* W  = net ? W_v    : W_u;
    const float mx  = mu[j], my = mu[UNITS + j];
    const float b   = be[j], wgt = W[j];

    // validity of deg-6 approx over safety box [-0.05,1.05]^2
    const float xlo = -0.05f, xhi = 1.05f;
    const float dxl = xlo - mx, dxh = xhi - mx;
    const float dyl = xlo - my, dyh = xhi - my;
    const float dx2max = fmaxf(dxl*dxl, dxh*dxh);
    const float dy2max = fmaxf(dyl*dyl, dyh*dyh);
    const float dx2min = (dxl <= 0.f && dxh >= 0.f) ? 0.f : fminf(dxl*dxl, dxh*dxh);
    const float dy2min = (dyl <= 0.f && dyh >= 0.f) ? 0.f : fminf(dyl*dyl, dyh*dyh);
    const float t1 = b * (dx2min + dy2min);
    const float t2 = b * (dx2max + dy2max);
    const float tlo = fminf(t1, t2), thi = fmaxf(t1, t2);
    const int bad = !(thi <= 2.4f && tlo >= -0.2f);
    if (lane == 0) sflag[w] = bad;

    // quadratic t(X,Y), X = x-0.5, Y = y-0.5
    const float ax = mx - 0.5f, ay = my - 0.5f;
    const float qXX = b, qYY = b;
    const float qX = -2.f*b*ax, qY = -2.f*b*ay;
    const float q0 = b*(ax*ax + ay*ay);

    const float fourwb = 4.f * wgt * b;
    float cP[8], cL[8];
    #pragma unroll
    for (int m = 0; m < 8; ++m) {
        cP[m] = wgt * CC[m];
        cL[m] = fourwb * ((m ? CC[m-1] : 0.f) - CC[m]);
    }

    float* A = &pwA[w][0];
    float* B = &pwB[w][0];
    #pragma unroll
    for (int r = 0; r < 4; ++r) {
        const int c = cidx[r];
        if (c < NCO) {
            float v = 0.f;
            if (c == 0)          v = q0;
            else if (c == 1)     v = qY;
            else if (c == 2)     v = qYY;
            else if (c == STR)   v = qX;
            else if (c == 2*STR) v = qXX;
            A[c] = v;
        }
    }
    __threadfence_block();

    float aP[4] = {0,0,0,0}, aL[4] = {0,0,0,0};
    #pragma unroll
    for (int r = 0; r < 4; ++r)
        if (cidx[r] == 0) { aP[r] = cP[0]; aL[r] = cL[0]; }

    #pragma unroll
    for (int m = 1; m <= 7; ++m) {
        #pragma unroll
        for (int r = 0; r < 4; ++r) {
            const int c = cidx[r];
            if (c < NCO) {
                const float p = A[c];
                aP[r] = fmaf(cP[m], p, aP[r]);
                aL[r] = fmaf(cL[m], p, aL[r]);
            }
        }
        if (m < 7) {
            #pragma unroll
            for (int r = 0; r < 4; ++r) {
                const int c = cidx[r];
                if (c < NCO) {
                    float acc = q0 * A[c];
                    if (gm[r] >= 1) acc = fmaf(qY,  A[c-1],     acc);
                    if (gm[r] >= 2) acc = fmaf(qYY, A[c-2],     acc);
                    if (gi[r] >= 1) acc = fmaf(qX,  A[c-STR],   acc);
                    if (gi[r] >= 2) acc = fmaf(qXX, A[c-2*STR], acc);
                    B[c] = acc;
                }
            }
            float* T = A; A = B; B = T;
            __threadfence_block();
        }
    }

    // ---- stage per-wave accs, single combined write pass ----
    __syncthreads();
    #pragma unroll
    for (int r = 0; r < 4; ++r) {
        const int c = cidx[r];
        if (c < NCO) { pwA[w][c] = aP[r]; pwB[w][c] = aL[r]; }
    }
    __syncthreads();
    {
        float* dst = partial + bid * CFTOT;
        #pragma unroll
        for (int k = 0; k < 4; ++k) {
            const int c = tid + 256 * k;
            if (c < CFTOT) {
                float v = 0.f;
                int idx, isLap, nsel;
                if (c < 208)      { idx = c;       isLap = 0; nsel = 0; }
                else if (c < 448) { idx = c - 208; isLap = 1; nsel = 0; }
                else if (c < 656) { idx = c - 448; isLap = 0; nsel = 1; }
                else              { idx = c - 656; isLap = 1; nsel = 1; }
                const int i = idx >> 4, m = idx & 15;
                if (m < 15) {
                    const int cs = i * STR + m;
                    if (!isLap) v = pwA[nsel][cs] + pwA[2 + nsel][cs];
                    else        v = pwB[nsel][cs] + pwB[2 + nsel][cs];
                }
                dst[c] = v;
            }
        }
    }
    if (tid == 0)
        flagBlk[bid] = sflag[0] | sflag[1] | sflag[2] | sflag[3];
}

// ---------------------------------------------------------------------------
// fold: 128 block-partials -> coefF (fixed order) + flagAll. 4 blocks.
// ---------------------------------------------------------------------------
__global__ __launch_bounds__(256) void rbf_fold(
    const float* __restrict__ partial, const int* __restrict__ flagBlk,
    float* __restrict__ coefF, int* __restrict__ flagAll)
{
    const int tid = threadIdx.x;
    const int c   = blockIdx.x * 256 + tid;
    if (c < CFTOT) {
        float s = 0.f;
        #pragma unroll 8
        for (int p = 0; p < PBLK; ++p)
            s += partial[p * CFTOT + c];
        coefF[c] = s;
    }
    if (blockIdx.x == 0 && tid < 128) {
        int f = flagBlk[tid];
        for (int off = 32; off > 0; off >>= 1)
            f |= __shfl_down(f, off);
        __shared__ int ff[2];
        if ((tid & 63) == 0) ff[tid >> 6] = f;
        __syncthreads();
        if (tid == 0) *flagAll = ff[0] | ff[1];
    }
}

// ---------------------------------------------------------------------------
// eval4: padded (stride-16) bivariate poly, total degree D, at 4 points.
// One ds_read_b128 (uniform broadcast) feeds 16 FMAs; 4 independent
// Horner chains hide LDS latency at 1 wave/SIMD. (R17-proven)
// ---------------------------------------------------------------------------
template<int D>
__device__ __forceinline__ void eval4(const float* sco,
    float X0, float X1, float X2, float X3,
    float Y0, float Y1, float Y2, float Y3,
    float& h0, float& h1, float& h2, float& h3)
{
    h0 = h1 = h2 = h3 = 0.f;
    #pragma unroll
    for (int ii = 0; ii <= D; ++ii) {
        const int i = D - ii;                 // row, high X-degree first
        const int K = (D - i + 4) / 4;        // quads needed in this row
        float r0 = 0.f, r1 = 0.f, r2 = 0.f, r3 = 0.f;
        #pragma unroll
        for (int kk = 0; kk < K; ++kk) {
            const int k = K - 1 - kk;
            const float4 q = *(const float4*)(sco + i*LSTR + 4*k);
            r0 = fmaf(r0, Y0, q.w); r1 = fmaf(r1, Y1, q.w);
            r2 = fmaf(r2, Y2, q.w); r3 = fmaf(r3, Y3, q.w);
            r0 = fmaf(r0, Y0, q.z); r1 = fmaf(r1, Y1, q.z);
            r2 = fmaf(r2, Y2, q.z); r3 = fmaf(r3, Y3, q.z);
            r0 = fmaf(r0, Y0, q.y); r1 = fmaf(r1, Y1, q.y);
            r2 = fmaf(r2, Y2, q.y); r3 = fmaf(r3, Y3, q.y);
            r0 = fmaf(r0, Y0, q.x); r1 = fmaf(r1, Y1, q.x);
            r2 = fmaf(r2, Y2, q.x); r3 = fmaf(r3, Y3, q.x);
        }
        h0 = fmaf(h0, X0, r0); h1 = fmaf(h1, X1, r1);
        h2 = fmaf(h2, X2, r2); h3 = fmaf(h3, X3, r3);
    }
}

__global__ __launch_bounds__(MTPB) void rbf_main(
    const float* __restrict__ gx, const float* __restrict__ gy,
    const float* __restrict__ gu, const float* __restrict__ gv,
    const float* __restrict__ gdu, const float* __restrict__ gdv,
    const float* __restrict__ coefF, const int* __restrict__ flagAll,
    const float* __restrict__ mu_u, const float* __restrict__ beta_u,
    const float* __restrict__ W_u,
    const float* __restrict__ mu_v, const float* __restrict__ beta_v,
    const float* __restrict__ W_v,
    const float* __restrict__ p_d, const float* __restrict__ p_a,
    const float* __restrict__ p_b, const float* __restrict__ p_um,
    const float* __restrict__ p_vm, const float* __restrict__ p_us,
    const float* __restrict__ p_vs,
    float* __restrict__ part)
{
    const int tid = threadIdx.x;
    const int bid = blockIdx.x;
    const int i0  = bid * MTPB + tid;

    __shared__ __align__(16) float sco[CFTOT];  // 3.6 KB coef table
    if (tid < CFTOT/4)
        ((float4*)sco)[tid] = ((const float4*)coefF)[tid];
    __syncthreads();

    float xs[PPT], ys[PPT];
    #pragma unroll
    for (int p = 0; p < PPT; ++p) {
        xs[p] = gx[i0 + p*QSTRIDE];
        ys[p] = gy[i0 + p*QSTRIDE];
    }

    const int bad = __builtin_amdgcn_readfirstlane(*flagAll);
    bool in = true;
    #pragma unroll
    for (int p = 0; p < PPT; ++p)
        in = in && (xs[p] >= -0.05f) && (xs[p] <= 1.05f)
                && (ys[p] >= -0.05f) && (ys[p] <= 1.05f);
    const bool allIn = __all(in);

    float up[PPT], vp[PPT], lu[PPT], lv[PPT];
    if (!bad && allIn) {
        const float X0 = xs[0]-0.5f, X1 = xs[1]-0.5f, X2 = xs[2]-0.5f, X3 = xs[3]-0.5f;
        const float Y0 = ys[0]-0.5f, Y1 = ys[1]-0.5f, Y2 = ys[2]-0.5f, Y3 = ys[3]-0.5f;
        eval4<12>(sco + OFF_PU, X0,X1,X2,X3, Y0,Y1,Y2,Y3, up[0],up[1],up[2],up[3]);
        eval4<14>(sco + OFF_LU, X0,X1,X2,X3, Y0,Y1,Y2,Y3, lu[0],lu[1],lu[2],lu[3]);
        eval4<12>(sco + OFF_PV, X0,X1,X2,X3, Y0,Y1,Y2,Y3, vp[0],vp[1],vp[2],vp[3]);
        eval4<14>(sco + OFF_LV, X0,X1,X2,X3, Y0,Y1,Y2,Y3, lv[0],lv[1],lv[2],lv[3]);
    } else {
        // exact whole-wave fallback (never taken for in-distribution inputs)
        #pragma unroll
        for (int p = 0; p < PPT; ++p) { up[p]=lu[p]=vp[p]=lv[p]=0.f; }
        for (int jj = 0; jj < UNITS; ++jj) {
            const float mxu = mu_u[jj], myu = mu_u[UNITS + jj];
            const float bu_ = beta_u[jj], wu_ = W_u[jj];
            const float mxv = mu_v[jj], myv = mu_v[UNITS + jj];
            const float bv_ = beta_v[jj], wv_ = W_v[jj];
            #pragma unroll
            for (int p = 0; p < PPT; ++p) {
                {
                    const float dx = xs[p] - mxu, dy = ys[p] - myu;
                    const float r2 = fmaf(dx, dx, dy * dy);
                    const float ph = expf(-bu_ * r2);
                    up[p] = fmaf(wu_, ph, up[p]);
                    lu[p] = fmaf(wu_ * ph, fmaf(4.f*bu_*bu_, r2, -4.f*bu_), lu[p]);
                }
                {
                    const float dx = xs[p] - mxv, dy = ys[p] - myv;
                    const float r2 = fmaf(dx, dx, dy * dy);
                    const float ph = expf(-bv_ * r2);
                    vp[p] = fmaf(wv_, ph, vp[p]);
                    lv[p] = fmaf(wv_ * ph, fmaf(4.f*bv_*bv_, r2, -4.f*bv_), lv[p]);
                }
            }
        }
    }

    // ---- residuals ----
    const float dd = p_d[0],  aa = p_a[0], bb = p_b[0];
    const float um = p_um[0], vm = p_vm[0];
    const float us = p_us[0], vs = p_vs[0];
    const float iu  = 1.0f / us, iv = 1.0f / vs;
    const float cau = (aa - um) * iu;
    const float c4b = 4.0f * bb * iu;
    const float cbv = bb * iv;

    float s0 = 0.f, s1 = 0.f, s2 = 0.f, s3 = 0.f, s4 = 0.f, s5 = 0.f;
    #pragma unroll
    for (int p = 0; p < PPT; ++p) {
        const int ii = i0 + p*QSTRIDE;
        const float uu  = gu[ii],  vv  = gv[ii];
        const float ddu = gdu[ii], ddv = gdv[ii];
        float eu = up[p] - uu; s0 += eu * eu;
        float ev = vp[p] - vv; s1 += ev * ev;
        float uph = fmaf(up[p], us, um);
        float vph = fmaf(vp[p], vs, vm);
        float den = fmaf(uph, uph, 1.0f);
        float uvd = uph * vph / den;
        float rpu = fmaf(dd, lu[p], cau) - up[p] - c4b * uvd;
        s2 += rpu * rpu;
        float rdu = lu[p] - ddu; s3 += rdu * rdu;
        float rpv = fmaf(uph, iv, lv[p]) - cbv * uvd;
        s4 += rpv * rpv;
        float rdv = lv[p] - ddv; s5 += rdv * rdv;
    }

    // ---- block reduction (deterministic) ----
    float s[6] = { s0, s1, s2, s3, s4, s5 };
    __shared__ float red[4][6];
    #pragma unroll
    for (int k = 0; k < 6; ++k) {
        float vsum = s[k];
        for (int off = 32; off > 0; off >>= 1)
            vsum += __shfl_down(vsum, off);
        s[k] = vsum;
    }
    const int lane = tid & 63;
    const int wid  = tid >> 6;
    if (lane == 0) {
        #pragma unroll
        for (int k = 0; k < 6; ++k) red[wid][k] = s[k];
    }
    __syncthreads();
    if (tid < 6) {
        float p = red[0][tid] + red[1][tid] + red[2][tid] + red[3][tid];
        part[tid * MBLK + bid] = p;
    }
}

__global__ __launch_bounds__(256) void rbf_final(
    const float* __restrict__ part, float* __restrict__ out)
{
    const int tid = threadIdx.x;
    __shared__ float red[4][6];
    float s[6];
    #pragma unroll
    for (int k = 0; k < 6; ++k) {
        float vsum = part[k * MBLK + tid];
        for (int off = 32; off > 0; off >>= 1)
            vsum += __shfl_down(vsum, off);
        s[k] = vsum;
    }
    const int lane = tid & 63;
    const int wid  = tid >> 6;
    if (lane == 0) {
        #pragma unroll
        for (int k = 0; k < 6; ++k) red[wid][k] = s[k];
    }
    __syncthreads();
    if (tid == 0) {
        const float inv = 1.0f / (float)NPTS;
        const float Lu  = (red[0][0] + red[1][0] + red[2][0] + red[3][0]) * inv;
        const float Lv  = (red[0][1] + red[1][1] + red[2][1] + red[3][1]) * inv;
        const float Lpu = (red[0][2] + red[1][2] + red[2][2] + red[3][2]) * inv;
        const float Ldu = (red[0][3] + red[1][3] + red[2][3] + red[3][3]) * inv;
        const float Lpv = (red[0][4] + red[1][4] + red[2][4] + red[3][4]) * inv;
        const float Ldv = (red[0][5] + red[1][5] + red[2][5] + red[3][5]) * inv;
        out[0] = 0.1f * Lu + 0.1f * Lv + Lpu + Ldu + Lpv + Ldv;
        out[1] = Lu;
        out[2] = Lpu;
        out[3] = Lv;
        out[4] = Lpv;
        out[5] = Ldu;
        out[6] = Ldv;
    }
}

extern "C" void kernel_launch(void* const* d_in, const int* in_sizes, int n_in,
                              void* d_out, int out_size, void* d_ws, size_t ws_size,
                              hipStream_t stream) {
    const float* gx   = (const float*)d_in[0];
    const float* gy   = (const float*)d_in[1];
    const float* gu   = (const float*)d_in[2];
    const float* gv   = (const float*)d_in[3];
    const float* gdu  = (const float*)d_in[4];
    const float* gdv  = (const float*)d_in[5];
    const float* mu_u = (const float*)d_in[6];
    const float* be_u = (const float*)d_in[7];
    const float* W_u  = (const float*)d_in[8];
    const float* mu_v = (const float*)d_in[9];
    const float* be_v = (const float*)d_in[10];
    const float* W_v  = (const float*)d_in[11];
    const float* p_d  = (const float*)d_in[12];
    const float* p_a  = (const float*)d_in[13];
    const float* p_b  = (const float*)d_in[14];
    const float* p_um = (const float*)d_in[15];
    const float* p_vm = (const float*)d_in[16];
    const float* p_us = (const float*)d_in[17];
    const float* p_vs = (const float*)d_in[18];

    float* wsf     = (float*)d_ws;
    float* partial = wsf;                        // 128*896 = 114688 floats
    float* coefF   = wsf + 114688;               // 896 floats (16B aligned)
    float* part    = wsf + 115584;               // 6*256 floats
    int*   flagBlk = (int*)(wsf + 117120);       // 128 ints
    int*   flagAll = (int*)(wsf + 117248);       // 1 int
    float* out     = (float*)d_out;              // 7 floats

    rbf_prep<<<PBLK, 256, 0, stream>>>(mu_u, be_u, W_u, mu_v, be_v, W_v,
                                       partial, flagBlk);
    rbf_fold<<<4, 256, 0, stream>>>(partial, flagBlk, coefF, flagAll);
    rbf_main<<<MBLK, MTPB, 0, stream>>>(gx, gy, gu, gv, gdu, gdv,
                                        coefF, flagAll,
                                        mu_u, be_u, W_u, mu_v, be_v, W_v,
                                        p_d, p_a, p_b, p_um, p_vm, p_us, p_vs,
                                        part);
    rbf_final<<<1, 256, 0, stream>>>(part, out);
}